// Round 11
// baseline (80.122 us; speedup 1.0000x reference)
//
#include <hip/hip_runtime.h>
#include <hip/hip_bf16.h>
#include <cstdint>

// ---------------- problem constants ----------------
#define BB 1024          // batch
#define DD 512           // dim
#define CC 50000         // classes
#define CCP 50048        // padded classes (782 * 64)
#define NTN 782          // n-tiles (BN=64)
#define NBLK 256         // 8 m-tiles * 32 splits = 1 block/CU exactly (persistent)
#define SCALE_F 64.0f
#define COS_M_F 0.87758256189037276f
#define SIN_M_F 0.47942553860420301f
#define TH_F   (-0.87758256189037276f)
#define MM_F   0.23971276930210156f

typedef __attribute__((ext_vector_type(4))) int i32x4;
typedef __attribute__((ext_vector_type(8))) char char8;

// ---------------- ws layout (bytes) ----------------
#define OFF_RS   ((size_t)0)                          // [1024] float row sum-exp accum
#define OFF_ES   (OFF_RS + 4096)                      // [1024] float (e scales)
#define OFF_WS   (OFF_ES + 4096)                      // [50048] float (w scales, padded)
#define OFF_EI8  (OFF_WS + 204800)                    // [1024][512] i8
#define OFF_WI8  (OFF_EI8 + (size_t)BB*DD)            // [50048][512] i8 (padded)

// ---------------- kernel 1: fused normalize+quantize + init -------------------
__global__ void quant_kernel(const float* __restrict__ emb, const float* __restrict__ wgt,
                             char* __restrict__ ei8, float* __restrict__ es,
                             char* __restrict__ wi8, float* __restrict__ wsc,
                             float* __restrict__ rowsum, float* __restrict__ out) {
    const int blk = blockIdx.x;
    if (blk == 12756) {
        const int t = threadIdx.x;   // 256
        #pragma unroll
        for (int i = 0; i < 4; ++i) rowsum[i * 256 + t] = 0.f;
        if (t == 0) out[0] = 0.f;
        // zero pad rows 50000..50047 (24576 B): 96 B per thread
        int4* pz = reinterpret_cast<int4*>(wi8 + (size_t)CC * DD + t * 96);
        #pragma unroll
        for (int i = 0; i < 6; ++i) pz[i] = (int4){0, 0, 0, 0};
        if (t < CCP - CC) wsc[CC + t] = 0.f;
        return;
    }
    const int r4 = threadIdx.x >> 6;
    const int l  = threadIdx.x & 63;
    const bool isw = blk < 12500;
    const int row = isw ? (blk * 4 + r4) : ((blk - 12500) * 4 + r4);
    const float* src = (isw ? wgt : emb) + (size_t)row * DD;
    const float4* r = reinterpret_cast<const float4*>(src);
    float4 v0 = r[l * 2 + 0];
    float4 v1 = r[l * 2 + 1];
    float ss = v0.x*v0.x + v0.y*v0.y + v0.z*v0.z + v0.w*v0.w
             + v1.x*v1.x + v1.y*v1.y + v1.z*v1.z + v1.w*v1.w;
    float mx = fmaxf(fmaxf(fmaxf(fabsf(v0.x), fabsf(v0.y)), fmaxf(fabsf(v0.z), fabsf(v0.w))),
                     fmaxf(fmaxf(fabsf(v1.x), fabsf(v1.y)), fmaxf(fabsf(v1.z), fabsf(v1.w))));
    #pragma unroll
    for (int m = 1; m < 64; m <<= 1) {
        ss += __shfl_xor(ss, m);
        mx = fmaxf(mx, __shfl_xor(mx, m));
    }
    float nrm = fmaxf(sqrtf(ss), 1e-12f);
    float ma  = fmaxf(mx, 1e-20f);
    float qs  = 127.0f / ma;
    if (l == 0) (isw ? wsc : es)[row] = ma / (127.0f * nrm);
    char8 q;
    q[0]=(char)__float2int_rn(v0.x*qs); q[1]=(char)__float2int_rn(v0.y*qs);
    q[2]=(char)__float2int_rn(v0.z*qs); q[3]=(char)__float2int_rn(v0.w*qs);
    q[4]=(char)__float2int_rn(v1.x*qs); q[5]=(char)__float2int_rn(v1.y*qs);
    q[6]=(char)__float2int_rn(v1.z*qs); q[7]=(char)__float2int_rn(v1.w*qs);
    *reinterpret_cast<char8*>((isw ? wi8 : ei8) + (size_t)row * DD + l * 8) = q;
}

// ---------------- kernel 2: i8 GEMM, ring-buffered counted-vmcnt pipeline ------
// 256 persistent blocks (8 m-tiles x 32 splits), 1 block/CU, 512 thr = 8 waves
// (4m x 2n); wave tile 32x32. A: af[2][8]=64 VGPR loaded once. B: 3-buffer LDS
// ring (3 x 32 KB), stage tile i+2 during round i, end-of-round s_waitcnt
// vmcnt(4) leaves the fresh stage in flight (T4) -> barrier never waits on HBM/L2.
// wsc pre-staged to LDS so epilogue reads are lgkm (vmcnt stays countable).
__global__ __launch_bounds__(512, 2) void arc_gemm_i8_kernel(
        const char* __restrict__ ei8,    // [1024][512] i8
        const char* __restrict__ wi8,    // [50048][512] i8 (padded)
        const float* __restrict__ es,    // [1024]
        const float* __restrict__ wsc,   // [50048] (padded)
        float* __restrict__ rowsum)      // [1024]
{
    __shared__ __align__(16) char lds[3][32768];
    __shared__ float ldsW[1600];         // up to 25 rounds * 64 w-scales

    const int t   = threadIdx.x;       // 0..511
    const int wid = t >> 6;
    const int wm  = wid >> 1;          // 0..3 (32-row chunk)
    const int wn  = wid & 1;           // 0..1 (32-col chunk)
    const int l   = t & 63;
    const int r16 = l & 15;
    const int kg  = l >> 4;

    // XCD-bijective: XCD k hosts splits [4k,4k+4) x all 8 m-tiles (3.2 MB W in L2)
    const int bid  = blockIdx.x;
    const int bidp = (bid & 7) * 32 + (bid >> 3);
    const int mt = bidp & 7;           // m-tile 0..7
    const int sp = bidp >> 3;          // split 0..31
    const int m0 = mt * 128;
    const int nt0 = (sp < 14) ? sp * 25 : sp * 24 + 14;
    const int cnt = (sp < 14) ? 25 : 24;

    // ---- A fragments: 2 m-frags x 8 kk, 16 B each -> 64 VGPR ----
    i32x4 af[2][8];
    #pragma unroll
    for (int fm = 0; fm < 2; ++fm)
        #pragma unroll
        for (int kk = 0; kk < 8; ++kk)
            af[fm][kk] = *reinterpret_cast<const i32x4*>(
                ei8 + (size_t)(m0 + wm * 32 + fm * 16 + r16) * DD + kk * 64 + kg * 16);

    // ---- per-row e-scale hoist ----
    float se_r[2][4];
    #pragma unroll
    for (int fm = 0; fm < 2; ++fm)
        #pragma unroll
        for (int j = 0; j < 4; ++j)
            se_r[fm][j] = es[m0 + wm * 32 + fm * 16 + kg * 4 + j];

    float rs[2][4];
    #pragma unroll
    for (int fm = 0; fm < 2; ++fm)
        #pragma unroll
        for (int j = 0; j < 4; ++j) rs[fm][j] = 0.f;

    // ---- pre-stage this block's w-scales into LDS (keeps vmcnt countable) ----
    for (int j = t; j < cnt * 64; j += 512)
        ldsW[j] = wsc[nt0 * 64 + j];

    // ---- persistent stage pointers (tiles contiguous: +32768 B per round) ----
    const char* sp4[4];
    #pragma unroll
    for (int i = 0; i < 4; ++i) {
        int flat = (i * 512 + t) * 16;
        int kk2  = flat >> 13;
        int row  = (flat >> 7) & 63;
        int col  = flat & 127;
        int scol = col ^ ((row & 7) << 4);
        sp4[i] = wi8 + (size_t)(nt0 * 64 + row) * DD + kk2 * 128 + scol;
    }
    auto stageB = [&](int buf) {
        #pragma unroll
        for (int i = 0; i < 4; ++i) {
            __builtin_amdgcn_global_load_lds(
                (const __attribute__((address_space(1))) void*)sp4[i],
                (__attribute__((address_space(3))) void*)(&lds[buf][(i * 512 + t) * 16]),
                16, 0, 0);
            sp4[i] += 64 * DD;
        }
    };

    // ---- prologue: stage tiles 0,1; wait only for tile 0 (vmcnt(4)) ----
    stageB(0);
    stageB(1);
    asm volatile("s_waitcnt vmcnt(4)" ::: "memory");
    __builtin_amdgcn_s_barrier();

    int cur = 0;
    for (int i = 0; i < cnt; ++i) {
        int stg = cur + 2; if (stg >= 3) stg -= 3;
        if (i + 2 < cnt) stageB(stg);          // prefetch 2 ahead, stays in flight

        // ---- compute: 8 kk, B from lds[cur], A from regs ----
        i32x4 acc[2][2];
        #pragma unroll
        for (int fm = 0; fm < 2; ++fm)
            #pragma unroll
            for (int fn = 0; fn < 2; ++fn) acc[fm][fn] = (i32x4){0, 0, 0, 0};
        #pragma unroll
        for (int kk = 0; kk < 8; ++kk) {
            i32x4 b[2];
            #pragma unroll
            for (int fn = 0; fn < 2; ++fn) {
                int row = wn * 32 + fn * 16 + r16;
                int off = (kk >> 1) * 8192 + row * 128
                        + (((kk & 1) * 64 + kg * 16) ^ ((row & 7) << 4));
                b[fn] = *reinterpret_cast<const i32x4*>(&lds[cur][off]);
            }
            #pragma unroll
            for (int fm = 0; fm < 2; ++fm)
                #pragma unroll
                for (int fn = 0; fn < 2; ++fn)
                    acc[fm][fn] = __builtin_amdgcn_mfma_i32_16x16x64_i8(af[fm][kk], b[fn], acc[fm][fn], 0, 0, 0);
        }

        // ---- epilogue: rs += exp(fma(d, se*sw*64, -64)); sw from LDS (lgkm) ----
        float sw64_0 = ldsW[i * 64 + wn * 32 + r16]      * SCALE_F;
        float sw64_1 = ldsW[i * 64 + wn * 32 + r16 + 16] * SCALE_F;
        #pragma unroll
        for (int fm = 0; fm < 2; ++fm)
            #pragma unroll
            for (int j = 0; j < 4; ++j) {
                float k0 = se_r[fm][j] * sw64_0;
                float k1 = se_r[fm][j] * sw64_1;
                rs[fm][j] += __expf(fmaf((float)acc[fm][0][j], k0, -SCALE_F));
                rs[fm][j] += __expf(fmaf((float)acc[fm][1][j], k1, -SCALE_F));
            }

        // ---- T4 counted wait: tile i+1 landed (issued last round); leave i+2 ----
        if (i + 2 < cnt)      { asm volatile("s_waitcnt vmcnt(4)" ::: "memory"); }
        else if (i + 1 < cnt) { asm volatile("s_waitcnt vmcnt(0)" ::: "memory"); }
        __builtin_amdgcn_s_barrier();
        cur += 1; if (cur >= 3) cur -= 3;
    }

    // ---- block end: shfl-reduce over r16, one atomicAdd per row per wave ----
    #pragma unroll
    for (int fm = 0; fm < 2; ++fm) {
        #pragma unroll
        for (int j = 0; j < 4; ++j) {
            float v = rs[fm][j];
            #pragma unroll
            for (int mk = 1; mk < 16; mk <<= 1) v += __shfl_xor(v, mk);
            if (r16 == 0) {
                int grow = m0 + wm * 32 + fm * 16 + kg * 4 + j;
                atomicAdd(&rowsum[grow], v);
            }
        }
    }
}

// ---------------- kernel 3: finish = labfix + nll + mean (atomic) ----------------
__global__ void finish_kernel(const char* __restrict__ ei8, const char* __restrict__ wi8,
                              const float* __restrict__ es, const float* __restrict__ wsc,
                              const int* __restrict__ labels,
                              const float* __restrict__ rowsum, float* __restrict__ out) {
    const int b = blockIdx.x;          // 1024 blocks
    const int l = threadIdx.x;         // 64 threads
    const int lab = labels[b];
    char8 a = *reinterpret_cast<const char8*>(ei8 + (size_t)b * DD + l * 8);
    char8 w = *reinterpret_cast<const char8*>(wi8 + (size_t)lab * DD + l * 8);
    int d = 0;
    #pragma unroll
    for (int k = 0; k < 8; ++k) d += (int)a[k] * (int)w[k];
    #pragma unroll
    for (int m = 1; m < 64; m <<= 1) d += __shfl_xor(d, m);
    if (l == 0) {
        // bit-match the GEMM's unmargined term: exp(fma(d, es*(wsc*64), -64))
        float kf  = es[b] * (wsc[lab] * SCALE_F);
        float sub = __expf(fmaf((float)d, kf, -SCALE_F));
        float cosv = (float)d * es[b] * wsc[lab];
        float c2 = fminf(fmaxf(cosv * cosv, 0.f), 1.f);
        float phi = cosv * COS_M_F - sqrtf(1.f - c2) * SIN_M_F;
        phi = (cosv > TH_F) ? phi : (cosv - MM_F);
        float ml = SCALE_F * phi;
        float Sf = rowsum[b] + __expf(ml - SCALE_F) - sub;
        float nll = -(ml - SCALE_F - logf(Sf));
        atomicAdd(out, nll * (1.0f / BB));
    }
}

// ---------------- launcher ----------------
extern "C" void kernel_launch(void* const* d_in, const int* in_sizes, int n_in,
                              void* d_out, int out_size, void* d_ws, size_t ws_size,
                              hipStream_t stream) {
    const float* emb    = (const float*)d_in[0];
    const int*   labels = (const int*)d_in[1];
    const float* wgt    = (const float*)d_in[2];
    float* out = (float*)d_out;
    char* ws = (char*)d_ws;

    float* rowsum = (float*)(ws + OFF_RS);
    float* es     = (float*)(ws + OFF_ES);
    float* wsc    = (float*)(ws + OFF_WS);
    char*  ei8    = (char*)(ws + OFF_EI8);
    char*  wi8    = (char*)(ws + OFF_WI8);

    quant_kernel<<<12757, 256, 0, stream>>>(emb, wgt, ei8, es, wi8, wsc, rowsum, out);
    arc_gemm_i8_kernel<<<NBLK, 512, 0, stream>>>(ei8, wi8, es, wsc, rowsum);
    finish_kernel<<<BB, 64, 0, stream>>>(ei8, wi8, es, wsc, labels, rowsum, out);
}